// Round 7
// baseline (34.657 us; speedup 1.0000x reference)
//
#include <hip/hip_runtime.h>
#include <math.h>

// RKN cell: B=4096, LOD=64, LSD=128, H=64, NB=15, NE=436 (band +-3)
#define O_PM   0
#define O_PCU  524288
#define O_PCL  786432
#define O_PCS  1048576
#define O_NM   1310720
#define O_NCU  1835008
#define O_NCL  2097152
#define O_NCS  2359296

// ws image (f32 words), consumption-layout, written by prep_kernel:
//  WS_W1 [0,8192):      [64 k2][64 j][2]  W1[j][2k2+s]
//  WS_W2 [8192,12288):  [32 k2][64 j][2]
//  WS_W3 [12288,13312): [32 k2][16 j][2]  (j=15 zero)
//  WS_BAS[13312,39472): [4 m][15 k][436 e]
//  WS_SPL[39472,39600): softplus(ltn) [128]
//  WS_B1 [39600,39664): b1[64];  WS_B2 [39664,39728): b2[64]
//  WS_B3 [39728,39744): b3 padded to 16 (j=15 zero)
#define WS_W1   0
#define WS_W2   8192
#define WS_W3   12288
#define WS_BAS  13312
#define WS_SPL  39472
#define WS_B1   39600
#define WS_B2   39664
#define WS_B3   39728
#define WS_TOT  39744

__device__ __forceinline__ float rlane(float v, int l) {
    return __uint_as_float(__builtin_amdgcn_readlane(__float_as_uint(v), l));
}
__device__ __forceinline__ unsigned short tobf(float a) {
    unsigned ua = __float_as_uint(a);
    ua += 0x7fffu + ((ua >> 16) & 1u);
    return (unsigned short)(ua >> 16);
}
__device__ __forceinline__ float frombf(unsigned short u) {
    return __uint_as_float(((unsigned)u) << 16);
}
__device__ __forceinline__ float frcp(float x) { return __builtin_amdgcn_rcpf(x); }
__device__ __forceinline__ float ftanh(float x) {
    float e = __expf(2.f * x);
    return 1.f - 2.f * frcp(e + 1.f);
}

// ---------------- prep: repack params into consumption layout ----------------
__global__ __launch_bounds__(256)
void prep_kernel(const float* __restrict__ W1, const float* __restrict__ W2,
                 const float* __restrict__ W3, const float* __restrict__ b1,
                 const float* __restrict__ b2, const float* __restrict__ b3,
                 const float* __restrict__ b11, const float* __restrict__ b12,
                 const float* __restrict__ b21, const float* __restrict__ b22,
                 const float* __restrict__ ltn, float* __restrict__ ws)
{
    const int t = blockIdx.x * 256 + threadIdx.x;
    if (t >= WS_TOT) return;
    float val = 0.f;
    if (t < 8192) {                        // W1 [k2][j][2]
        const int s = t & 1, j = (t >> 1) & 63, k2 = t >> 7;
        val = W1[j * 128 + 2 * k2 + s];
    } else if (t < 12288) {                // W2
        const int q = t - 8192;
        const int s = q & 1, j = (q >> 1) & 63, k2 = q >> 7;
        val = W2[j * 64 + 2 * k2 + s];
    } else if (t < 13312) {                // W3 (j padded to 16)
        const int q = t - 12288;
        const int s = q & 1, j = (q >> 1) & 15, k2 = q >> 5;
        if (j < 15) val = W3[j * 64 + 2 * k2 + s];
    } else if (t < 39472) {                // basis [m][k][e]
        const int q = t - 13312;
        const int e = q % 436, kk = q / 436;
        const int m = kk / 15, k = kk % 15;
        const float* bp = (m == 0) ? b11 : (m == 1) ? b12 : (m == 2) ? b21 : b22;
        val = bp[k * 436 + e];
    } else if (t < 39600) {                // softplus(ltn)
        val = logf(expf(ltn[t - 39472]) + 1.f);
    } else if (t < 39664) {
        val = b1[t - 39600];
    } else if (t < 39728) {
        val = b2[t - 39664];
    } else {
        const int j = t - 39728;
        if (j < 15) val = b3[j];
    }
    ws[t] = val;
}

// ---------------- main: 1024 blocks x 256 thr, 4 rows/block ----------------
// No weight LDS; weights/basis stream from L2 (52KB+104KB shared images).
// LDS = 4832 words = 19328 B:
//  [0,3488)  tmv bf16 [16 mr][436]
//  [3488,4000) pm_s [4][128] f32
//  [4000,4256) pcu_s; [4256,4512) pcl_s; [4512,4768) pcs_s  [4][64]
//  [4768,4832) coef_s [4][16]
__global__ __launch_bounds__(256, 4)
void rkn_kernel(const float* __restrict__ prior_mean,
                const float* __restrict__ cov_u,
                const float* __restrict__ cov_l,
                const float* __restrict__ cov_s,
                const float* __restrict__ obs,
                const float* __restrict__ obs_var,
                const float* __restrict__ ws,
                float* __restrict__ out)
{
    __shared__ __align__(16) unsigned smem[4832];
    unsigned short* tmv = (unsigned short*)smem;
    float* pm_s   = (float*)(smem + 3488);
    float* pcu_s  = (float*)(smem + 4000);
    float* pcl_s  = (float*)(smem + 4256);
    float* pcs_s  = (float*)(smem + 4512);
    float* coef_s = (float*)(smem + 4768);

    const int tid  = threadIdx.x;
    const int wid  = tid >> 6;          // wave = row within block (0..3)
    const int lane = tid & 63;
    const int row  = blockIdx.x * 4 + wid;
    const int jj   = lane & 15;
    const float2* ws2 = (const float2*)ws;

    // ---- per-row input loads (coalesced) ----
    const float cu   = cov_u[row * 64 + lane];
    const float cl   = cov_l[row * 64 + lane];
    const float cs   = cov_s[row * 64 + lane];
    const float ob   = obs[row * 64 + lane];
    const float ov   = obs_var[row * 64 + lane];
    const float pmu0 = prior_mean[row * 128 + lane];
    const float pml0 = prior_mean[row * 128 + 64 + lane];
    const float bias1 = ws[WS_B1 + lane];
    const float bias2 = ws[WS_B2 + lane];
    const float bias3 = ws[WS_B3 + jj];
    const float tcu   = ws[WS_SPL + lane];
    const float tcl   = ws[WS_SPL + 64 + lane];

    // ---- phase 1: Kalman update ----
    const float inv = frcp(cu + ov);
    const float qu  = cu * inv;
    const float ql  = cs * inv;
    const float res = ob - pmu0;
    const float pmu = pmu0 + qu * res;
    const float pml = pml0 + ql * res;
    const float cf  = 1.f - qu;
    const float pcu = cf * cu;
    const float pcl = cl - ql * cs;
    const float pcs = cf * cs;

    out[O_PM  + row * 128 + lane]      = pmu;
    out[O_PM  + row * 128 + 64 + lane] = pml;
    out[O_PCU + row * 64 + lane] = pcu;
    out[O_PCL + row * 64 + lane] = pcl;
    out[O_PCS + row * 64 + lane] = pcs;

    pm_s [wid * 128 + lane]      = pmu;     // consumed by same wave (phase 4)
    pm_s [wid * 128 + 64 + lane] = pml;
    pcu_s[wid * 64 + lane] = pcu;
    pcl_s[wid * 64 + lane] = pcl;
    pcs_s[wid * 64 + lane] = pcs;

    // ---- phase 2: MLP; f32 weight pairs from L2, readlane broadcast ----
    float a0 = bias1, a1 = 0.f, a2 = 0.f, a3 = 0.f;
#pragma unroll
    for (int k2 = 0; k2 < 64; ++k2) {
        const float2 w = ws2[(WS_W1 >> 1) + k2 * 64 + lane];
        const float src = (k2 < 32) ? pmu : pml;
        const int bl = (2 * k2) & 63;
        if (k2 & 1) { a2 += w.x * rlane(src, bl); a3 += w.y * rlane(src, bl + 1); }
        else        { a0 += w.x * rlane(src, bl); a1 += w.y * rlane(src, bl + 1); }
    }
    const float h1v = ftanh((a0 + a1) + (a2 + a3));

    a0 = bias2; a1 = 0.f; a2 = 0.f; a3 = 0.f;
#pragma unroll
    for (int k2 = 0; k2 < 32; ++k2) {
        const float2 w = ws2[(WS_W2 >> 1) + k2 * 64 + lane];
        const int bl = 2 * k2;
        if (k2 & 1) { a2 += w.x * rlane(h1v, bl); a3 += w.y * rlane(h1v, bl + 1); }
        else        { a0 += w.x * rlane(h1v, bl); a1 += w.y * rlane(h1v, bl + 1); }
    }
    const float h2v = ftanh((a0 + a1) + (a2 + a3));

    a0 = bias3; a1 = 0.f; a2 = 0.f; a3 = 0.f;
#pragma unroll
    for (int k2 = 0; k2 < 32; ++k2) {
        const float2 w = ws2[(WS_W3 >> 1) + k2 * 16 + jj];
        const int bl = 2 * k2;
        if (k2 & 1) { a2 += w.x * rlane(h2v, bl); a3 += w.y * rlane(h2v, bl + 1); }
        else        { a0 += w.x * rlane(h2v, bl); a1 += w.y * rlane(h2v, bl + 1); }
    }
    const float l3 = (a0 + a1) + (a2 + a3);    // logit jj lives in lane jj

    // ---- in-wave softmax (logit k in lane k, k<15) ----
    {
        float mx = rlane(l3, 0);
#pragma unroll
        for (int k = 1; k < 15; ++k) mx = fmaxf(mx, rlane(l3, k));
        const float ex = __expf(l3 - mx);
        float s = rlane(ex, 0);
#pragma unroll
        for (int k = 1; k < 15; ++k) s += rlane(ex, k);
        const float cval = ex * frcp(s);
        if (lane < 16) coef_s[wid * 16 + lane] = (lane < 15) ? cval : 0.f;
    }

    __syncthreads();   // [A] coeffs of all 4 rows visible

    // ---- phase 3: tm[m][r][e] = sum_k coeff[r][k]*basis_m[k][e], 2 e-passes ----
    {
        const float cv0 = coef_s[lane];     // (r,k) = (lane>>4, lane&15)

        // pass 0: e0 = tid (always active)
        float acc[4][4];
#pragma unroll
        for (int m = 0; m < 4; ++m)
#pragma unroll
            for (int r = 0; r < 4; ++r) acc[m][r] = 0.f;
#pragma unroll
        for (int k = 0; k < 15; ++k) {
            const float c0 = rlane(cv0, k);
            const float c1 = rlane(cv0, 16 + k);
            const float c2 = rlane(cv0, 32 + k);
            const float c3 = rlane(cv0, 48 + k);
#pragma unroll
            for (int m = 0; m < 4; ++m) {
                const float b = ws[WS_BAS + (m * 15 + k) * 436 + tid];
                acc[m][0] += c0 * b;
                acc[m][1] += c1 * b;
                acc[m][2] += c2 * b;
                acc[m][3] += c3 * b;
            }
        }
#pragma unroll
        for (int m = 0; m < 4; ++m)
#pragma unroll
            for (int r = 0; r < 4; ++r)
                tmv[(m * 4 + r) * 436 + tid] = tobf(acc[m][r]);

        // pass 1: e1 = tid + 256 (active if < 436)
        const int  e1   = tid + 256;
        const bool act1 = (e1 < 436);
        const int  e1c  = act1 ? e1 : 435;
#pragma unroll
        for (int m = 0; m < 4; ++m)
#pragma unroll
            for (int r = 0; r < 4; ++r) acc[m][r] = 0.f;
#pragma unroll
        for (int k = 0; k < 15; ++k) {
            const float c0 = rlane(cv0, k);
            const float c1 = rlane(cv0, 16 + k);
            const float c2 = rlane(cv0, 32 + k);
            const float c3 = rlane(cv0, 48 + k);
#pragma unroll
            for (int m = 0; m < 4; ++m) {
                const float b = ws[WS_BAS + (m * 15 + k) * 436 + e1c];
                acc[m][0] += c0 * b;
                acc[m][1] += c1 * b;
                acc[m][2] += c2 * b;
                acc[m][3] += c3 * b;
            }
        }
        if (act1) {
#pragma unroll
            for (int m = 0; m < 4; ++m)
#pragma unroll
                for (int r = 0; r < 4; ++r)
                    tmv[(m * 4 + r) * 436 + e1] = tobf(acc[m][r]);
        }
    }

    __syncthreads();   // [B] tm visible

    // ---- phase 4: banded mat-vec combos (wave=row, lane i=output dim) ----
    {
        const int i   = lane;
        const int jlo = (i - 3 > 0) ? (i - 3) : 0;
        const int ne  = ((i + 3 < 63) ? (i + 3) : 63) - jlo + 1;
        const int base = (i < 4)  ? (i * (i + 7)) / 2
                       : (i <= 61) ? (7 * i - 6)
                       : (i == 62) ? 427 : 432;

        float nmu = 0.f, nml = 0.f, ncu = 0.f, ncl = 0.f, ncs = 0.f;
#pragma unroll
        for (int d = 0; d < 7; ++d) {
            if (d < ne) {
                const int j  = jlo + d;
                const int eI = base + d;
                float t11 = frombf(tmv[(0 * 4 + wid) * 436 + eI]);
                float t12 = frombf(tmv[(1 * 4 + wid) * 436 + eI]);
                float t21 = frombf(tmv[(2 * 4 + wid) * 436 + eI]);
                float t22 = frombf(tmv[(3 * 4 + wid) * 436 + eI]);
                if (j == i) { t11 += 1.f; t22 += 1.f; }
                const float mu  = pm_s[wid * 128 + j];
                const float ml  = pm_s[wid * 128 + 64 + j];
                const float vcu = pcu_s[wid * 64 + j];
                const float vcl = pcl_s[wid * 64 + j];
                const float vcs = pcs_s[wid * 64 + j];
                nmu += t11 * mu + t12 * ml;
                nml += t21 * mu + t22 * ml;
                ncu += t11 * t11 * vcu + 2.f * t11 * t12 * vcs + t12 * t12 * vcl;
                ncl += t21 * t21 * vcu + 2.f * t21 * t22 * vcs + t22 * t22 * vcl;
                ncs += t21 * t11 * vcu + (t22 * t11 + t21 * t12) * vcs + t22 * t12 * vcl;
            }
        }
        out[O_NM  + row * 128 + i]      = nmu;
        out[O_NM  + row * 128 + 64 + i] = nml;
        out[O_NCU + row * 64 + i] = ncu + tcu;
        out[O_NCL + row * 64 + i] = ncl + tcl;
        out[O_NCS + row * 64 + i] = ncs;
    }
}

extern "C" void kernel_launch(void* const* d_in, const int* in_sizes, int n_in,
                              void* d_out, int out_size, void* d_ws, size_t ws_size,
                              hipStream_t stream) {
    float* ws = (float*)d_ws;
    prep_kernel<<<dim3(160), dim3(256), 0, stream>>>(
        (const float*)d_in[6],  // W1
        (const float*)d_in[8],  // W2
        (const float*)d_in[10], // W3
        (const float*)d_in[7],  // b1
        (const float*)d_in[9],  // b2
        (const float*)d_in[11], // b3
        (const float*)d_in[12], // tm11_basis
        (const float*)d_in[13], // tm12_basis
        (const float*)d_in[14], // tm21_basis
        (const float*)d_in[15], // tm22_basis
        (const float*)d_in[16], // log_trans_noise
        ws);
    rkn_kernel<<<dim3(1024), dim3(256), 0, stream>>>(
        (const float*)d_in[0],  // prior_mean
        (const float*)d_in[1],  // cov_u
        (const float*)d_in[2],  // cov_l
        (const float*)d_in[3],  // cov_s
        (const float*)d_in[4],  // obs
        (const float*)d_in[5],  // obs_var
        ws,
        (float*)d_out);
}

// Round 8
// 27.759 us; speedup vs baseline: 1.2485x; 1.2485x over previous
//
#include <hip/hip_runtime.h>
#include <math.h>

// RKN cell: B=4096, LOD=64, LSD=128, H=64, NB=15, NE=436 (band +-3)
#define O_PM   0
#define O_PCU  524288
#define O_PCL  786432
#define O_PCS  1048576
#define O_NM   1310720
#define O_NCU  1835008
#define O_NCL  2097152
#define O_NCS  2359296

__device__ __forceinline__ float rlane(float v, int l) {
    return __uint_as_float(__builtin_amdgcn_readlane(__float_as_uint(v), l));
}
__device__ __forceinline__ unsigned pk2(float a, float b) {   // 2xf32 -> 2xbf16 (RNE)
    unsigned ua = __float_as_uint(a), ub = __float_as_uint(b);
    ua += 0x7fffu + ((ua >> 16) & 1u);
    ub += 0x7fffu + ((ub >> 16) & 1u);
    return (ua >> 16) | (ub & 0xffff0000u);
}
__device__ __forceinline__ float lo16(unsigned w) { return __uint_as_float(w << 16); }
__device__ __forceinline__ float hi16(unsigned w) { return __uint_as_float(w & 0xffff0000u); }
__device__ __forceinline__ float frcp(float x) { return __builtin_amdgcn_rcpf(x); }
__device__ __forceinline__ float ftanh(float x) {
    float e = __expf(2.f * x);
    return 1.f - 2.f * frcp(e + 1.f);
}
// ds_swizzle xor within 16-lane groups (BitMode: (xor<<10)|(0<<5)|0x1F)
#define SWZ(v, imm) __uint_as_float((unsigned)__builtin_amdgcn_ds_swizzle((int)__float_as_uint(v), imm))

// 512 thr, 8 rows/block, 512 blocks, launch_bounds(512,4): 2 blocks/CU, 128 VGPR.
// LDS (u32 words) 9664 = 38656 B:
//  [0,6976)  weights bf16 image (6656 used): W1v[16k8][64j]u4 | W2v[8][64] | W3v[8][16]
//            UNION tmv uint2 [8 r][436 e] (= {pk2(t11,t12), pk2(t21,t22)})
//  [6976,8000) pm_s [8][128] f32
//  [8000,8512) pcu_s; [8512,9024) pcl_s; [9024,9536) pcs_s  [8][64]
//  [9536,9664) coef_s [8][16]
__global__ __launch_bounds__(512, 4)
void rkn_kernel(const float* __restrict__ prior_mean,
                const float* __restrict__ cov_u,
                const float* __restrict__ cov_l,
                const float* __restrict__ cov_s,
                const float* __restrict__ obs,
                const float* __restrict__ obs_var,
                const float* __restrict__ W1,
                const float* __restrict__ b1,
                const float* __restrict__ W2,
                const float* __restrict__ b2,
                const float* __restrict__ W3,
                const float* __restrict__ b3,
                const float* __restrict__ tm11b,
                const float* __restrict__ tm12b,
                const float* __restrict__ tm21b,
                const float* __restrict__ tm22b,
                const float* __restrict__ ltn,
                float* __restrict__ out)
{
    __shared__ __align__(16) unsigned smem[9664];
    uint4* lds4 = (uint4*)smem;
    uint4* W1v  = (uint4*)smem;              // [16 k8][64 j]
    uint4* W2v  = (uint4*)(smem + 4096);     // [8 k8][64 j]
    uint4* W3v  = (uint4*)(smem + 6144);     // [8 k8][16 j]
    uint2* tmv2 = (uint2*)smem;              // [8 r][436 e] (union with weights)
    float* pm_s   = (float*)(smem + 6976);
    float* pcu_s  = (float*)(smem + 8000);
    float* pcl_s  = (float*)(smem + 8512);
    float* pcs_s  = (float*)(smem + 9024);
    float* coef_s = (float*)(smem + 9536);

    const int tid  = threadIdx.x;
    const int wid  = tid >> 6;          // wave = row within block (0..7)
    const int lane = tid & 63;
    const int row  = blockIdx.x * 8 + wid;
    const int jj   = lane & 15;

    // ---- per-row input loads (coalesced) ----
    const float cu   = cov_u[row * 64 + lane];
    const float cl   = cov_l[row * 64 + lane];
    const float cs   = cov_s[row * 64 + lane];
    const float ob   = obs[row * 64 + lane];
    const float ov   = obs_var[row * 64 + lane];
    const float pmu0 = prior_mean[row * 128 + lane];
    const float pml0 = prior_mean[row * 128 + 64 + lane];
    const float bias1 = b1[lane];
    const float bias2 = b2[lane];
    const float bias3 = (jj < 15) ? b3[jj] : 0.f;

    // ---- basis -> 30 packed-bf16 u32 regs (single e per thread, 436<=512) ----
    const int e = (tid < 436) ? tid : 435;
    unsigned bas[32];
#pragma unroll
    for (int m = 0; m < 4; ++m) {
        const float* bp = (m == 0) ? tm11b : (m == 1) ? tm12b : (m == 2) ? tm21b : tm22b;
#pragma unroll
        for (int k2 = 0; k2 < 8; ++k2) {
            const float lo = bp[(2 * k2) * 436 + e];
            const float hi = (2 * k2 + 1 < 15) ? bp[(2 * k2 + 1) * 436 + e] : 0.f;
            bas[m * 8 + k2] = pk2(lo, hi);
        }
    }

    // ---- stage weight image: bf16-pack inline (1664 uint4) ----
#pragma unroll
    for (int it = 0; it < 4; ++it) {
        const int idx = tid + it * 512;
        if (idx < 1664) {
            uint4 v = make_uint4(0u, 0u, 0u, 0u);
            if (idx < 1024) {                 // W1
                const int j = idx & 63, k8 = idx >> 6;
                const float4* p = (const float4*)(W1 + j * 128 + k8 * 8);
                const float4 a = p[0], b = p[1];
                v = make_uint4(pk2(a.x, a.y), pk2(a.z, a.w), pk2(b.x, b.y), pk2(b.z, b.w));
            } else if (idx < 1536) {          // W2
                const int q = idx - 1024;
                const int j = q & 63, k8 = q >> 6;
                const float4* p = (const float4*)(W2 + j * 64 + k8 * 8);
                const float4 a = p[0], b = p[1];
                v = make_uint4(pk2(a.x, a.y), pk2(a.z, a.w), pk2(b.x, b.y), pk2(b.z, b.w));
            } else {                          // W3 (j=15 stays zero)
                const int q = idx - 1536;
                const int j = q & 15, k8 = q >> 4;
                if (j < 15) {
                    const float4* p = (const float4*)(W3 + j * 64 + k8 * 8);
                    const float4 a = p[0], b = p[1];
                    v = make_uint4(pk2(a.x, a.y), pk2(a.z, a.w), pk2(b.x, b.y), pk2(b.z, b.w));
                }
            }
            lds4[idx] = v;
        }
    }

    // softplus(trans noise)
    const float tcu = __logf(__expf(ltn[lane]) + 1.f);
    const float tcl = __logf(__expf(ltn[64 + lane]) + 1.f);

    // ---- phase 1: Kalman update ----
    const float inv = frcp(cu + ov);
    const float qu  = cu * inv;
    const float ql  = cs * inv;
    const float res = ob - pmu0;
    const float pmu = pmu0 + qu * res;
    const float pml = pml0 + ql * res;
    const float cf  = 1.f - qu;
    const float pcu = cf * cu;
    const float pcl = cl - ql * cs;
    const float pcs = cf * cs;

    out[O_PM  + row * 128 + lane]      = pmu;
    out[O_PM  + row * 128 + 64 + lane] = pml;
    out[O_PCU + row * 64 + lane] = pcu;
    out[O_PCL + row * 64 + lane] = pcl;
    out[O_PCS + row * 64 + lane] = pcs;

    pm_s [wid * 128 + lane]      = pmu;
    pm_s [wid * 128 + 64 + lane] = pml;
    pcu_s[wid * 64 + lane] = pcu;
    pcl_s[wid * 64 + lane] = pcl;
    pcs_s[wid * 64 + lane] = pcs;

    __syncthreads();   // weights staged + row state visible

    // ---- phase 2: MLP; 8-deep register-batched weight prefetch ----
    float a0 = bias1, a1 = 0.f, a2 = 0.f, a3 = 0.f;
    uint4 wb[8];
#pragma unroll
    for (int batch = 0; batch < 2; ++batch) {
        const float src = batch ? pml : pmu;
#pragma unroll
        for (int t = 0; t < 8; ++t) wb[t] = W1v[(batch * 8 + t) * 64 + lane];
#pragma unroll
        for (int t = 0; t < 8; ++t) {
            const int bl = t * 8;
            a0 += lo16(wb[t].x) * rlane(src, bl + 0);
            a1 += hi16(wb[t].x) * rlane(src, bl + 1);
            a2 += lo16(wb[t].y) * rlane(src, bl + 2);
            a3 += hi16(wb[t].y) * rlane(src, bl + 3);
            a0 += lo16(wb[t].z) * rlane(src, bl + 4);
            a1 += hi16(wb[t].z) * rlane(src, bl + 5);
            a2 += lo16(wb[t].w) * rlane(src, bl + 6);
            a3 += hi16(wb[t].w) * rlane(src, bl + 7);
        }
    }
    const float h1v = ftanh((a0 + a1) + (a2 + a3));

    a0 = bias2; a1 = 0.f; a2 = 0.f; a3 = 0.f;
#pragma unroll
    for (int t = 0; t < 8; ++t) wb[t] = W2v[t * 64 + lane];
#pragma unroll
    for (int t = 0; t < 8; ++t) {
        const int bl = t * 8;
        a0 += lo16(wb[t].x) * rlane(h1v, bl + 0);
        a1 += hi16(wb[t].x) * rlane(h1v, bl + 1);
        a2 += lo16(wb[t].y) * rlane(h1v, bl + 2);
        a3 += hi16(wb[t].y) * rlane(h1v, bl + 3);
        a0 += lo16(wb[t].z) * rlane(h1v, bl + 4);
        a1 += hi16(wb[t].z) * rlane(h1v, bl + 5);
        a2 += lo16(wb[t].w) * rlane(h1v, bl + 6);
        a3 += hi16(wb[t].w) * rlane(h1v, bl + 7);
    }
    const float h2v = ftanh((a0 + a1) + (a2 + a3));

    a0 = bias3; a1 = 0.f; a2 = 0.f; a3 = 0.f;
#pragma unroll
    for (int t = 0; t < 8; ++t) wb[t] = W3v[t * 16 + jj];
#pragma unroll
    for (int t = 0; t < 8; ++t) {
        const int bl = t * 8;
        a0 += lo16(wb[t].x) * rlane(h2v, bl + 0);
        a1 += hi16(wb[t].x) * rlane(h2v, bl + 1);
        a2 += lo16(wb[t].y) * rlane(h2v, bl + 2);
        a3 += hi16(wb[t].y) * rlane(h2v, bl + 3);
        a0 += lo16(wb[t].z) * rlane(h2v, bl + 4);
        a1 += hi16(wb[t].z) * rlane(h2v, bl + 5);
        a2 += lo16(wb[t].w) * rlane(h2v, bl + 6);
        a3 += hi16(wb[t].w) * rlane(h2v, bl + 7);
    }
    const float l3 = (a0 + a1) + (a2 + a3);   // logit jj lives in lane jj (dup x4)

    // ---- in-wave softmax via xor-swizzle tree over 16-lane groups ----
    {
        float mx = (jj < 15) ? l3 : -1e30f;
        mx = fmaxf(mx, SWZ(mx, 0x041F));
        mx = fmaxf(mx, SWZ(mx, 0x081F));
        mx = fmaxf(mx, SWZ(mx, 0x101F));
        mx = fmaxf(mx, SWZ(mx, 0x201F));
        const float ex = (jj < 15) ? __expf(l3 - mx) : 0.f;
        float s = ex;
        s += SWZ(s, 0x041F);
        s += SWZ(s, 0x081F);
        s += SWZ(s, 0x101F);
        s += SWZ(s, 0x201F);
        const float cval = ex * frcp(s);
        if (lane < 16) coef_s[wid * 16 + lane] = cval;   // jj==15 -> 0
    }

    __syncthreads();   // coeffs visible; weight region dead -> tmv reuse

    // ---- phase 3: tm[r][e][4m] = sum_k coeff[r][k]*basis_m[k][e] ----
    {
        const float cv0 = coef_s[lane];        // rows 0-3: (r,k)=(lane>>4,lane&15)
        const float cv1 = coef_s[64 + lane];   // rows 4-7
        float acc[4][8];
#pragma unroll
        for (int m = 0; m < 4; ++m)
#pragma unroll
            for (int r = 0; r < 8; ++r) acc[m][r] = 0.f;

#pragma unroll
        for (int k = 0; k < 15; ++k) {
            float c[8];
#pragma unroll
            for (int r = 0; r < 4; ++r) {
                c[r]     = rlane(cv0, r * 16 + k);
                c[4 + r] = rlane(cv1, r * 16 + k);
            }
#pragma unroll
            for (int m = 0; m < 4; ++m) {
                const unsigned bw = bas[m * 8 + (k >> 1)];
                const float b = (k & 1) ? hi16(bw) : lo16(bw);
#pragma unroll
                for (int r = 0; r < 8; ++r)
                    acc[m][r] += c[r] * b;
            }
        }
        if (tid < 436) {
#pragma unroll
            for (int r = 0; r < 8; ++r)
                tmv2[r * 436 + tid] = make_uint2(pk2(acc[0][r], acc[1][r]),
                                                 pk2(acc[2][r], acc[3][r]));
        }
    }

    __syncthreads();   // tm visible

    // ---- phase 4: banded mat-vec combos (wave=row, lane i=output dim) ----
    {
        const int i   = lane;
        const int jlo = (i - 3 > 0) ? (i - 3) : 0;
        const int ne  = ((i + 3 < 63) ? (i + 3) : 63) - jlo + 1;
        const int base = (i < 4)  ? (i * (i + 7)) / 2
                       : (i <= 61) ? (7 * i - 6)
                       : (i == 62) ? 427 : 432;

        float nmu = 0.f, nml = 0.f, ncu = 0.f, ncl = 0.f, ncs = 0.f;
#pragma unroll
        for (int d = 0; d < 7; ++d) {
            if (d < ne) {
                const int j  = jlo + d;
                const uint2 tv = tmv2[wid * 436 + base + d];
                float t11 = lo16(tv.x);
                float t12 = hi16(tv.x);
                float t21 = lo16(tv.y);
                float t22 = hi16(tv.y);
                if (j == i) { t11 += 1.f; t22 += 1.f; }
                const float mu  = pm_s[wid * 128 + j];
                const float ml  = pm_s[wid * 128 + 64 + j];
                const float vcu = pcu_s[wid * 64 + j];
                const float vcl = pcl_s[wid * 64 + j];
                const float vcs = pcs_s[wid * 64 + j];
                nmu += t11 * mu + t12 * ml;
                nml += t21 * mu + t22 * ml;
                ncu += t11 * t11 * vcu + 2.f * t11 * t12 * vcs + t12 * t12 * vcl;
                ncl += t21 * t21 * vcu + 2.f * t21 * t22 * vcs + t22 * t22 * vcl;
                ncs += t21 * t11 * vcu + (t22 * t11 + t21 * t12) * vcs + t22 * t12 * vcl;
            }
        }
        out[O_NM  + row * 128 + i]      = nmu;
        out[O_NM  + row * 128 + 64 + i] = nml;
        out[O_NCU + row * 64 + i] = ncu + tcu;
        out[O_NCL + row * 64 + i] = ncl + tcl;
        out[O_NCS + row * 64 + i] = ncs;
    }
}

extern "C" void kernel_launch(void* const* d_in, const int* in_sizes, int n_in,
                              void* d_out, int out_size, void* d_ws, size_t ws_size,
                              hipStream_t stream) {
    rkn_kernel<<<dim3(512), dim3(512), 0, stream>>>(
        (const float*)d_in[0],  // prior_mean
        (const float*)d_in[1],  // cov_u
        (const float*)d_in[2],  // cov_l
        (const float*)d_in[3],  // cov_s
        (const float*)d_in[4],  // obs
        (const float*)d_in[5],  // obs_var
        (const float*)d_in[6],  // W1
        (const float*)d_in[7],  // b1
        (const float*)d_in[8],  // W2
        (const float*)d_in[9],  // b2
        (const float*)d_in[10], // W3
        (const float*)d_in[11], // b3
        (const float*)d_in[12], // tm11_basis
        (const float*)d_in[13], // tm12_basis
        (const float*)d_in[14], // tm21_basis
        (const float*)d_in[15], // tm22_basis
        (const float*)d_in[16], // log_trans_noise
        (float*)d_out);
}

// Round 9
// 26.655 us; speedup vs baseline: 1.3002x; 1.0414x over previous
//
#include <hip/hip_runtime.h>
#include <math.h>

// RKN cell: B=4096, LOD=64, LSD=128, H=64, NB=15, NE=436 (band +-3)
#define O_PM   0
#define O_PCU  524288
#define O_PCL  786432
#define O_PCS  1048576
#define O_NM   1310720
#define O_NCU  1835008
#define O_NCL  2097152
#define O_NCS  2359296

__device__ __forceinline__ float rlane(float v, int l) {
    return __uint_as_float(__builtin_amdgcn_readlane(__float_as_uint(v), l));
}
__device__ __forceinline__ unsigned pk2(float a, float b) {   // 2xf32 -> 2xbf16 (RNE)
    unsigned ua = __float_as_uint(a), ub = __float_as_uint(b);
    ua += 0x7fffu + ((ua >> 16) & 1u);
    ub += 0x7fffu + ((ub >> 16) & 1u);
    return (ua >> 16) | (ub & 0xffff0000u);
}
__device__ __forceinline__ float lo16(unsigned w) { return __uint_as_float(w << 16); }
__device__ __forceinline__ float hi16(unsigned w) { return __uint_as_float(w & 0xffff0000u); }
__device__ __forceinline__ float frcp(float x) { return __builtin_amdgcn_rcpf(x); }
__device__ __forceinline__ float ftanh(float x) {
    float e = __expf(2.f * x);
    return 1.f - 2.f * frcp(e + 1.f);
}
// ds_swizzle xor within 16-lane groups (BitMode: (xor<<10)|(0<<5)|0x1F)
#define SWZ(v, imm) __uint_as_float((unsigned)__builtin_amdgcn_ds_swizzle((int)__float_as_uint(v), imm))

// 512 thr, 8 rows/block, 512 blocks, launch_bounds(512,4): 2 blocks/CU, 128 VGPR.
// LDS (u32 words) 9664 = 38656 B:
//  [0,6976)  weights bf16 image (6656 used): W1v[16k8][64j]u4 | W2v[8][64] | W3v[8][16]
//            UNION tmv uint2 [8 r][436 e] (= {pk2(t11,t12), pk2(t21,t22)})
//  [6976,8000) pm_s [8][128] f32
//  [8000,8512) pcu_s; [8512,9024) pcl_s; [9024,9536) pcs_s  [8][64]
//  [9536,9664) coef_s [8][16]
// STAGING (R9 fix): global reads are lane-consecutive float4 (fully coalesced);
// the k-transpose happens on the LDS-write side (adjacent-word pairs -> b64).
__global__ __launch_bounds__(512, 4)
void rkn_kernel(const float* __restrict__ prior_mean,
                const float* __restrict__ cov_u,
                const float* __restrict__ cov_l,
                const float* __restrict__ cov_s,
                const float* __restrict__ obs,
                const float* __restrict__ obs_var,
                const float* __restrict__ W1,
                const float* __restrict__ b1,
                const float* __restrict__ W2,
                const float* __restrict__ b2,
                const float* __restrict__ W3,
                const float* __restrict__ b3,
                const float* __restrict__ tm11b,
                const float* __restrict__ tm12b,
                const float* __restrict__ tm21b,
                const float* __restrict__ tm22b,
                const float* __restrict__ ltn,
                float* __restrict__ out)
{
    __shared__ __align__(16) unsigned smem[9664];
    uint4* W1v  = (uint4*)smem;              // [16 k8][64 j]
    uint4* W2v  = (uint4*)(smem + 4096);     // [8 k8][64 j]
    uint4* W3v  = (uint4*)(smem + 6144);     // [8 k8][16 j]
    uint2* tmv2 = (uint2*)smem;              // [8 r][436 e] (union with weights)
    float* pm_s   = (float*)(smem + 6976);
    float* pcu_s  = (float*)(smem + 8000);
    float* pcl_s  = (float*)(smem + 8512);
    float* pcs_s  = (float*)(smem + 9024);
    float* coef_s = (float*)(smem + 9536);

    const int tid  = threadIdx.x;
    const int wid  = tid >> 6;          // wave = row within block (0..7)
    const int lane = tid & 63;
    const int row  = blockIdx.x * 8 + wid;
    const int jj   = lane & 15;

    // ---- per-row input loads (coalesced) ----
    const float cu   = cov_u[row * 64 + lane];
    const float cl   = cov_l[row * 64 + lane];
    const float cs   = cov_s[row * 64 + lane];
    const float ob   = obs[row * 64 + lane];
    const float ov   = obs_var[row * 64 + lane];
    const float pmu0 = prior_mean[row * 128 + lane];
    const float pml0 = prior_mean[row * 128 + 64 + lane];
    const float bias1 = b1[lane];
    const float bias2 = b2[lane];
    const float bias3 = (jj < 15) ? b3[jj] : 0.f;

    // ---- basis -> 30 packed-bf16 u32 regs (lane-consecutive e: coalesced) ----
    const int e = (tid < 436) ? tid : 435;
    unsigned bas[32];
#pragma unroll
    for (int m = 0; m < 4; ++m) {
        const float* bp = (m == 0) ? tm11b : (m == 1) ? tm12b : (m == 2) ? tm21b : tm22b;
#pragma unroll
        for (int k2 = 0; k2 < 8; ++k2) {
            const float lo = bp[(2 * k2) * 436 + e];
            const float hi = (2 * k2 + 1 < 15) ? bp[(2 * k2 + 1) * 436 + e] : 0.f;
            bas[m * 8 + k2] = pk2(lo, hi);
        }
    }

    // ---- stage weights: COALESCED global float4 reads, transposed LDS writes ----
    {
        const float4* W1q = (const float4*)W1;     // 2048 float4 (64 j x 32)
#pragma unroll
        for (int it = 0; it < 4; ++it) {
            const int idx = it * 512 + tid;        // lane-consecutive
            const float4 v = W1q[idx];
            const int j  = idx >> 5;               // 32 float4 per j-row
            const int kq = idx & 31;               // float4 index in k
            const int k2 = kq * 2;                 // even
            const int base = (k2 >> 2) * 256 + j * 4 + (k2 & 3);
            smem[base]     = pk2(v.x, v.y);
            smem[base + 1] = pk2(v.z, v.w);        // adjacent -> ds_write_b64
        }
        const float4* W2q = (const float4*)W2;     // 1024 float4 (64 j x 16)
#pragma unroll
        for (int it = 0; it < 2; ++it) {
            const int idx = it * 512 + tid;
            const float4 v = W2q[idx];
            const int j  = idx >> 4;
            const int kq = idx & 15;
            const int k2 = kq * 2;
            const int base = 4096 + (k2 >> 2) * 256 + j * 4 + (k2 & 3);
            smem[base]     = pk2(v.x, v.y);
            smem[base + 1] = pk2(v.z, v.w);
        }
        if (tid < 256) {                           // W3: 15 j x 16 float4 (+pad j=15)
            const int j  = tid >> 4;
            const int kq = tid & 15;
            float4 v = make_float4(0.f, 0.f, 0.f, 0.f);
            if (j < 15) v = ((const float4*)W3)[j * 16 + kq];
            const int k2 = kq * 2;
            const int base = 6144 + (k2 >> 2) * 64 + j * 4 + (k2 & 3);
            smem[base]     = pk2(v.x, v.y);
            smem[base + 1] = pk2(v.z, v.w);
        }
    }

    // softplus(trans noise)
    const float tcu = __logf(__expf(ltn[lane]) + 1.f);
    const float tcl = __logf(__expf(ltn[64 + lane]) + 1.f);

    // ---- phase 1: Kalman update ----
    const float inv = frcp(cu + ov);
    const float qu  = cu * inv;
    const float ql  = cs * inv;
    const float res = ob - pmu0;
    const float pmu = pmu0 + qu * res;
    const float pml = pml0 + ql * res;
    const float cf  = 1.f - qu;
    const float pcu = cf * cu;
    const float pcl = cl - ql * cs;
    const float pcs = cf * cs;

    out[O_PM  + row * 128 + lane]      = pmu;
    out[O_PM  + row * 128 + 64 + lane] = pml;
    out[O_PCU + row * 64 + lane] = pcu;
    out[O_PCL + row * 64 + lane] = pcl;
    out[O_PCS + row * 64 + lane] = pcs;

    pm_s [wid * 128 + lane]      = pmu;
    pm_s [wid * 128 + 64 + lane] = pml;
    pcu_s[wid * 64 + lane] = pcu;
    pcl_s[wid * 64 + lane] = pcl;
    pcs_s[wid * 64 + lane] = pcs;

    __syncthreads();   // weights staged + row state visible

    // ---- phase 2: MLP; 8-deep register-batched weight prefetch ----
    float a0 = bias1, a1 = 0.f, a2 = 0.f, a3 = 0.f;
    uint4 wb[8];
#pragma unroll
    for (int batch = 0; batch < 2; ++batch) {
        const float src = batch ? pml : pmu;
#pragma unroll
        for (int t = 0; t < 8; ++t) wb[t] = W1v[(batch * 8 + t) * 64 + lane];
#pragma unroll
        for (int t = 0; t < 8; ++t) {
            const int bl = t * 8;
            a0 += lo16(wb[t].x) * rlane(src, bl + 0);
            a1 += hi16(wb[t].x) * rlane(src, bl + 1);
            a2 += lo16(wb[t].y) * rlane(src, bl + 2);
            a3 += hi16(wb[t].y) * rlane(src, bl + 3);
            a0 += lo16(wb[t].z) * rlane(src, bl + 4);
            a1 += hi16(wb[t].z) * rlane(src, bl + 5);
            a2 += lo16(wb[t].w) * rlane(src, bl + 6);
            a3 += hi16(wb[t].w) * rlane(src, bl + 7);
        }
    }
    const float h1v = ftanh((a0 + a1) + (a2 + a3));

    a0 = bias2; a1 = 0.f; a2 = 0.f; a3 = 0.f;
#pragma unroll
    for (int t = 0; t < 8; ++t) wb[t] = W2v[t * 64 + lane];
#pragma unroll
    for (int t = 0; t < 8; ++t) {
        const int bl = t * 8;
        a0 += lo16(wb[t].x) * rlane(h1v, bl + 0);
        a1 += hi16(wb[t].x) * rlane(h1v, bl + 1);
        a2 += lo16(wb[t].y) * rlane(h1v, bl + 2);
        a3 += hi16(wb[t].y) * rlane(h1v, bl + 3);
        a0 += lo16(wb[t].z) * rlane(h1v, bl + 4);
        a1 += hi16(wb[t].z) * rlane(h1v, bl + 5);
        a2 += lo16(wb[t].w) * rlane(h1v, bl + 6);
        a3 += hi16(wb[t].w) * rlane(h1v, bl + 7);
    }
    const float h2v = ftanh((a0 + a1) + (a2 + a3));

    a0 = bias3; a1 = 0.f; a2 = 0.f; a3 = 0.f;
#pragma unroll
    for (int t = 0; t < 8; ++t) wb[t] = W3v[t * 16 + jj];
#pragma unroll
    for (int t = 0; t < 8; ++t) {
        const int bl = t * 8;
        a0 += lo16(wb[t].x) * rlane(h2v, bl + 0);
        a1 += hi16(wb[t].x) * rlane(h2v, bl + 1);
        a2 += lo16(wb[t].y) * rlane(h2v, bl + 2);
        a3 += hi16(wb[t].y) * rlane(h2v, bl + 3);
        a0 += lo16(wb[t].z) * rlane(h2v, bl + 4);
        a1 += hi16(wb[t].z) * rlane(h2v, bl + 5);
        a2 += lo16(wb[t].w) * rlane(h2v, bl + 6);
        a3 += hi16(wb[t].w) * rlane(h2v, bl + 7);
    }
    const float l3 = (a0 + a1) + (a2 + a3);   // logit jj lives in lane jj (dup x4)

    // ---- in-wave softmax via xor-swizzle tree over 16-lane groups ----
    {
        float mx = (jj < 15) ? l3 : -1e30f;
        mx = fmaxf(mx, SWZ(mx, 0x041F));
        mx = fmaxf(mx, SWZ(mx, 0x081F));
        mx = fmaxf(mx, SWZ(mx, 0x101F));
        mx = fmaxf(mx, SWZ(mx, 0x201F));
        const float ex = (jj < 15) ? __expf(l3 - mx) : 0.f;
        float s = ex;
        s += SWZ(s, 0x041F);
        s += SWZ(s, 0x081F);
        s += SWZ(s, 0x101F);
        s += SWZ(s, 0x201F);
        const float cval = ex * frcp(s);
        if (lane < 16) coef_s[wid * 16 + lane] = cval;   // jj==15 -> 0
    }

    __syncthreads();   // coeffs visible; weight region dead -> tmv reuse

    // ---- phase 3: tm[r][e][4m] = sum_k coeff[r][k]*basis_m[k][e] ----
    {
        const float cv0 = coef_s[lane];        // rows 0-3: (r,k)=(lane>>4,lane&15)
        const float cv1 = coef_s[64 + lane];   // rows 4-7
        float acc[4][8];
#pragma unroll
        for (int m = 0; m < 4; ++m)
#pragma unroll
            for (int r = 0; r < 8; ++r) acc[m][r] = 0.f;

#pragma unroll
        for (int k = 0; k < 15; ++k) {
            float c[8];
#pragma unroll
            for (int r = 0; r < 4; ++r) {
                c[r]     = rlane(cv0, r * 16 + k);
                c[4 + r] = rlane(cv1, r * 16 + k);
            }
#pragma unroll
            for (int m = 0; m < 4; ++m) {
                const unsigned bw = bas[m * 8 + (k >> 1)];
                const float b = (k & 1) ? hi16(bw) : lo16(bw);
#pragma unroll
                for (int r = 0; r < 8; ++r)
                    acc[m][r] += c[r] * b;
            }
        }
        if (tid < 436) {
#pragma unroll
            for (int r = 0; r < 8; ++r)
                tmv2[r * 436 + tid] = make_uint2(pk2(acc[0][r], acc[1][r]),
                                                 pk2(acc[2][r], acc[3][r]));
        }
    }

    __syncthreads();   // tm visible

    // ---- phase 4: banded mat-vec combos (wave=row, lane i=output dim) ----
    {
        const int i   = lane;
        const int jlo = (i - 3 > 0) ? (i - 3) : 0;
        const int ne  = ((i + 3 < 63) ? (i + 3) : 63) - jlo + 1;
        const int base = (i < 4)  ? (i * (i + 7)) / 2
                       : (i <= 61) ? (7 * i - 6)
                       : (i == 62) ? 427 : 432;

        float nmu = 0.f, nml = 0.f, ncu = 0.f, ncl = 0.f, ncs = 0.f;
#pragma unroll
        for (int d = 0; d < 7; ++d) {
            if (d < ne) {
                const int j  = jlo + d;
                const uint2 tv = tmv2[wid * 436 + base + d];
                float t11 = lo16(tv.x);
                float t12 = hi16(tv.x);
                float t21 = lo16(tv.y);
                float t22 = hi16(tv.y);
                if (j == i) { t11 += 1.f; t22 += 1.f; }
                const float mu  = pm_s[wid * 128 + j];
                const float ml  = pm_s[wid * 128 + 64 + j];
                const float vcu = pcu_s[wid * 64 + j];
                const float vcl = pcl_s[wid * 64 + j];
                const float vcs = pcs_s[wid * 64 + j];
                nmu += t11 * mu + t12 * ml;
                nml += t21 * mu + t22 * ml;
                ncu += t11 * t11 * vcu + 2.f * t11 * t12 * vcs + t12 * t12 * vcl;
                ncl += t21 * t21 * vcu + 2.f * t21 * t22 * vcs + t22 * t22 * vcl;
                ncs += t21 * t11 * vcu + (t22 * t11 + t21 * t12) * vcs + t22 * t12 * vcl;
            }
        }
        out[O_NM  + row * 128 + i]      = nmu;
        out[O_NM  + row * 128 + 64 + i] = nml;
        out[O_NCU + row * 64 + i] = ncu + tcu;
        out[O_NCL + row * 64 + i] = ncl + tcl;
        out[O_NCS + row * 64 + i] = ncs;
    }
}

extern "C" void kernel_launch(void* const* d_in, const int* in_sizes, int n_in,
                              void* d_out, int out_size, void* d_ws, size_t ws_size,
                              hipStream_t stream) {
    rkn_kernel<<<dim3(512), dim3(512), 0, stream>>>(
        (const float*)d_in[0],  // prior_mean
        (const float*)d_in[1],  // cov_u
        (const float*)d_in[2],  // cov_l
        (const float*)d_in[3],  // cov_s
        (const float*)d_in[4],  // obs
        (const float*)d_in[5],  // obs_var
        (const float*)d_in[6],  // W1
        (const float*)d_in[7],  // b1
        (const float*)d_in[8],  // W2
        (const float*)d_in[9],  // b2
        (const float*)d_in[10], // W3
        (const float*)d_in[11], // b3
        (const float*)d_in[12], // tm11_basis
        (const float*)d_in[13], // tm12_basis
        (const float*)d_in[14], // tm21_basis
        (const float*)d_in[15], // tm22_basis
        (const float*)d_in[16], // log_trans_noise
        (float*)d_out);
}

// Round 10
// 25.748 us; speedup vs baseline: 1.3460x; 1.0352x over previous
//
#include <hip/hip_runtime.h>
#include <math.h>

// RKN cell: B=4096, LOD=64, LSD=128, H=64, NB=15, NE=436 (band +-3)
// R10: full-MFMA rewrite. 256 blocks x 512 thr, 16 rows/block.
#define O_PM   0
#define O_PCU  524288
#define O_PCL  786432
#define O_PCS  1048576
#define O_NM   1310720
#define O_NCU  1835008
#define O_NCL  2097152
#define O_NCS  2359296

// ---- LDS word map (39296 words = 157184 B, 1 block/CU) ----
// W1L [64 j][76 w] (128 bf16 used/row); W2L/W3L [.][44 w] (64 used)
// tm [16 r][872 w] = [16][1744] bf16  -- UNION with weights (dead after layer3)
// BAST [1744 n][10 w] = [n][20 u16]: basisT[n=4e+m][k], k<15 valid, k=15 zeroed
// PMB bf16 [16][76 w]; H1/H2 bf16 [16][44 w]; COEF [16][10 w] (20 u16)
// PMF f32 [16][128]; CUF/CLF/CSF f32 [16][64]
#define L_W1   0
#define L_W2   4864
#define L_W3   7680
#define L_TM   0
#define L_BAST 13952
#define L_PMB  31392
#define L_H1   32608
#define L_H2   33312
#define L_COEF 34016
#define L_PMF  34176
#define L_CUF  36224
#define L_CLF  37248
#define L_CSF  38272
#define L_TOT  39296

typedef short s8v __attribute__((ext_vector_type(8)));
typedef short s4v __attribute__((ext_vector_type(4)));
typedef float f4v __attribute__((ext_vector_type(4)));

__device__ __forceinline__ unsigned pk2(float a, float b) {   // 2xf32 -> 2xbf16 RNE
    unsigned ua = __float_as_uint(a), ub = __float_as_uint(b);
    ua += 0x7fffu + ((ua >> 16) & 1u);
    ub += 0x7fffu + ((ub >> 16) & 1u);
    return (ua >> 16) | (ub & 0xffff0000u);
}
__device__ __forceinline__ unsigned short tobf(float a) {
    unsigned ua = __float_as_uint(a);
    ua += 0x7fffu + ((ua >> 16) & 1u);
    return (unsigned short)(ua >> 16);
}
__device__ __forceinline__ float frombf(unsigned short u) {
    return __uint_as_float(((unsigned)u) << 16);
}
__device__ __forceinline__ float lo16(unsigned w) { return __uint_as_float(w << 16); }
__device__ __forceinline__ float hi16(unsigned w) { return __uint_as_float(w & 0xffff0000u); }
__device__ __forceinline__ float frcp(float x) { return __builtin_amdgcn_rcpf(x); }
__device__ __forceinline__ float ftanh(float x) {
    float e = __expf(2.f * x);
    return 1.f - 2.f * frcp(e + 1.f);
}
#define SWZ(v, imm) __uint_as_float((unsigned)__builtin_amdgcn_ds_swizzle((int)__float_as_uint(v), imm))

#if __has_builtin(__builtin_amdgcn_mfma_f32_16x16x16_bf16)
#define MFMA16(A,B,C) __builtin_amdgcn_mfma_f32_16x16x16_bf16(A,B,C,0,0,0)
#define HAVE_MFMA16 1
#elif __has_builtin(__builtin_amdgcn_mfma_f32_16x16x16bf16_1k)
#define MFMA16(A,B,C) __builtin_amdgcn_mfma_f32_16x16x16bf16_1k(A,B,C,0,0,0)
#define HAVE_MFMA16 1
#else
#define HAVE_MFMA16 0
#endif

// waves 4-7 stage basisT chunks: q in [lo*256, hi*256) covering 6540 float4s
__device__ __forceinline__ void stage_bast(unsigned* smem, int tid2, int lo, int hi,
        const float* __restrict__ b11, const float* __restrict__ b12,
        const float* __restrict__ b21, const float* __restrict__ b22)
{
    unsigned short* bu = (unsigned short*)(smem + L_BAST);
    for (int it = lo; it < hi; ++it) {
        const int q = it * 256 + tid2;
        if (q < 6540) {
            const int m   = q / 1635;
            const int rem = q - m * 1635;
            const int k   = rem / 109;
            const int eq  = rem - k * 109;
            const float* bp = (m == 0) ? b11 : (m == 1) ? b12 : (m == 2) ? b21 : b22;
            const float4 v = *(const float4*)(bp + k * 436 + eq * 4);
            const int n0 = eq * 16 + m;                 // n = 4*(eq*4+i)+m
            bu[(n0     ) * 20 + k] = tobf(v.x);
            bu[(n0 +  4) * 20 + k] = tobf(v.y);
            bu[(n0 +  8) * 20 + k] = tobf(v.z);
            bu[(n0 + 12) * 20 + k] = tobf(v.w);
        }
    }
}

__global__ __launch_bounds__(512, 2)
void rkn_kernel(const float* __restrict__ prior_mean,
                const float* __restrict__ cov_u,
                const float* __restrict__ cov_l,
                const float* __restrict__ cov_s,
                const float* __restrict__ obs,
                const float* __restrict__ obs_var,
                const float* __restrict__ W1,
                const float* __restrict__ b1,
                const float* __restrict__ W2,
                const float* __restrict__ b2,
                const float* __restrict__ W3,
                const float* __restrict__ b3,
                const float* __restrict__ tm11b,
                const float* __restrict__ tm12b,
                const float* __restrict__ tm21b,
                const float* __restrict__ tm22b,
                const float* __restrict__ ltn,
                float* __restrict__ out)
{
    __shared__ __align__(16) unsigned smem[L_TOT];

    const int tid  = threadIdx.x;
    const int wid  = tid >> 6;
    const int lane = tid & 63;
    const int lrow = lane & 15;     // MFMA operand row (A row / B col)
    const int lkg  = lane >> 4;     // k-group

    // ---- stage weights: coalesced float4 reads, bf16-pair LDS writes ----
    {
#pragma unroll
        for (int it = 0; it < 4; ++it) {              // W1: 2048 float4
            const int idx = it * 512 + tid;
            const float4 v = ((const float4*)W1)[idx];
            const int j = idx >> 5, kq = idx & 31;
            unsigned* d = smem + (L_W1 + j * 76 + kq * 2);
            d[0] = pk2(v.x, v.y); d[1] = pk2(v.z, v.w);
        }
#pragma unroll
        for (int it = 0; it < 2; ++it) {              // W2: 1024 float4
            const int idx = it * 512 + tid;
            const float4 v = ((const float4*)W2)[idx];
            const int j = idx >> 4, kq = idx & 15;
            unsigned* d = smem + (L_W2 + j * 44 + kq * 2);
            d[0] = pk2(v.x, v.y); d[1] = pk2(v.z, v.w);
        }
        if (tid < 240) {                              // W3: 15 j x 16 float4
            const float4 v = ((const float4*)W3)[tid];
            const int j = tid >> 4, kq = tid & 15;
            unsigned* d = smem + (L_W3 + j * 44 + kq * 2);
            d[0] = pk2(v.x, v.y); d[1] = pk2(v.z, v.w);
        } else if (tid < 284) {                       // zero W3 row 15
            smem[L_W3 + 15 * 44 + (tid - 240)] = 0u;
        }
    }

    // ---- phase 1: Kalman (row = tid>>5, dims pd,pd+1) ----
    const int prow  = tid >> 5;
    const int pd    = (tid & 31) << 1;
    const int grow1 = blockIdx.x * 16 + prow;
    {
        const float2 cu2 = *(const float2*)(cov_u   + grow1 * 64 + pd);
        const float2 cl2 = *(const float2*)(cov_l   + grow1 * 64 + pd);
        const float2 cs2 = *(const float2*)(cov_s   + grow1 * 64 + pd);
        const float2 ob2 = *(const float2*)(obs     + grow1 * 64 + pd);
        const float2 ov2 = *(const float2*)(obs_var + grow1 * 64 + pd);
        const float2 pu2 = *(const float2*)(prior_mean + grow1 * 128 + pd);
        const float2 pl2 = *(const float2*)(prior_mean + grow1 * 128 + 64 + pd);

        const float i0 = frcp(cu2.x + ov2.x), i1 = frcp(cu2.y + ov2.y);
        const float qu0 = cu2.x * i0, qu1 = cu2.y * i1;
        const float ql0 = cs2.x * i0, ql1 = cs2.y * i1;
        const float r0 = ob2.x - pu2.x, r1 = ob2.y - pu2.y;
        const float pmu0 = pu2.x + qu0 * r0, pmu1 = pu2.y + qu1 * r1;
        const float pml0 = pl2.x + ql0 * r0, pml1 = pl2.y + ql1 * r1;
        const float cf0 = 1.f - qu0, cf1 = 1.f - qu1;
        const float pcu0 = cf0 * cu2.x, pcu1 = cf1 * cu2.y;
        const float pcl0 = cl2.x - ql0 * cs2.x, pcl1 = cl2.y - ql1 * cs2.y;
        const float pcs0 = cf0 * cs2.x, pcs1 = cf1 * cs2.y;

        *(float2*)(out + O_PM  + grow1 * 128 + pd)      = make_float2(pmu0, pmu1);
        *(float2*)(out + O_PM  + grow1 * 128 + 64 + pd) = make_float2(pml0, pml1);
        *(float2*)(out + O_PCU + grow1 * 64 + pd) = make_float2(pcu0, pcu1);
        *(float2*)(out + O_PCL + grow1 * 64 + pd) = make_float2(pcl0, pcl1);
        *(float2*)(out + O_PCS + grow1 * 64 + pd) = make_float2(pcs0, pcs1);

        smem[L_PMB + prow * 76 + (pd >> 1)]      = pk2(pmu0, pmu1);
        smem[L_PMB + prow * 76 + 32 + (pd >> 1)] = pk2(pml0, pml1);
        *(float2*)((float*)(smem + L_PMF) + prow * 128 + pd)      = make_float2(pmu0, pmu1);
        *(float2*)((float*)(smem + L_PMF) + prow * 128 + 64 + pd) = make_float2(pml0, pml1);
        *(float2*)((float*)(smem + L_CUF) + prow * 64 + pd) = make_float2(pcu0, pcu1);
        *(float2*)((float*)(smem + L_CLF) + prow * 64 + pd) = make_float2(pcl0, pcl1);
        *(float2*)((float*)(smem + L_CSF) + prow * 64 + pd) = make_float2(pcs0, pcs1);
    }

    // softplus(trans noise) for phase 4 (per lane)
    const float tcu = __logf(__expf(ltn[lane]) + 1.f);
    const float tcl = __logf(__expf(ltn[64 + lane]) + 1.f);

    __syncthreads();   // B1: weights + pm staged

    // ---- MLP on waves 0-3 (one 16-col tile each) || basisT staging on 4-7 ----
    if (wid < 4) {
        const int w = wid;
        f4v acc = {0.f, 0.f, 0.f, 0.f};
#pragma unroll
        for (int s = 0; s < 4; ++s) {                 // layer1: K=128
            s8v a = *(const s8v*)(smem + L_PMB + lrow * 76 + s * 16 + lkg * 4);
            s8v b = *(const s8v*)(smem + L_W1 + (w * 16 + lrow) * 76 + s * 16 + lkg * 4);
            acc = __builtin_amdgcn_mfma_f32_16x16x32_bf16(a, b, acc, 0, 0, 0);
        }
        const float bc1 = b1[w * 16 + lrow];
        unsigned short* h1u = (unsigned short*)(smem + L_H1);
#pragma unroll
        for (int q = 0; q < 4; ++q)
            h1u[(lkg * 4 + q) * 88 + w * 16 + lrow] = tobf(ftanh(acc[q] + bc1));
    } else {
        stage_bast(smem, tid - 256, 0, 9, tm11b, tm12b, tm21b, tm22b);
    }
    __syncthreads();   // B2: h1 ready

    if (wid < 4) {
        const int w = wid;
        f4v acc = {0.f, 0.f, 0.f, 0.f};
#pragma unroll
        for (int s = 0; s < 2; ++s) {                 // layer2: K=64
            s8v a = *(const s8v*)(smem + L_H1 + lrow * 44 + s * 16 + lkg * 4);
            s8v b = *(const s8v*)(smem + L_W2 + (w * 16 + lrow) * 44 + s * 16 + lkg * 4);
            acc = __builtin_amdgcn_mfma_f32_16x16x32_bf16(a, b, acc, 0, 0, 0);
        }
        const float bc2 = b2[w * 16 + lrow];
        unsigned short* h2u = (unsigned short*)(smem + L_H2);
#pragma unroll
        for (int q = 0; q < 4; ++q)
            h2u[(lkg * 4 + q) * 88 + w * 16 + lrow] = tobf(ftanh(acc[q] + bc2));
    } else {
        stage_bast(smem, tid - 256, 9, 18, tm11b, tm12b, tm21b, tm22b);
    }
    __syncthreads();   // B3: h2 ready

    if (wid < 4) {
        f4v acc = {0.f, 0.f, 0.f, 0.f};
#pragma unroll
        for (int s = 0; s < 2; ++s) {                 // layer3: K=64, cols 0-14
            s8v a = *(const s8v*)(smem + L_H2 + lrow * 44 + s * 16 + lkg * 4);
            s8v b = *(const s8v*)(smem + L_W3 + lrow * 44 + s * 16 + lkg * 4);
            acc = __builtin_amdgcn_mfma_f32_16x16x32_bf16(a, b, acc, 0, 0, 0);
        }
        const float bc3 = (lrow < 15) ? b3[lrow] : 0.f;
        unsigned short* cfu = (unsigned short*)(smem + L_COEF);
#pragma unroll
        for (int q = 0; q < 4; ++q) {                 // in-frag softmax over cols
            const float lg = acc[q] + bc3;
            float v = (lrow < 15) ? lg : -1e30f;
            v = fmaxf(v, SWZ(v, 0x041F));
            v = fmaxf(v, SWZ(v, 0x081F));
            v = fmaxf(v, SWZ(v, 0x101F));
            v = fmaxf(v, SWZ(v, 0x201F));
            const float ex = (lrow < 15) ? __expf(lg - v) : 0.f;
            float ss = ex;
            ss += SWZ(ss, 0x041F);
            ss += SWZ(ss, 0x081F);
            ss += SWZ(ss, 0x101F);
            ss += SWZ(ss, 0x201F);
            if (wid == 0)
                cfu[(lkg * 4 + q) * 20 + lrow] = tobf(ex * frcp(ss));
        }
    } else {
        stage_bast(smem, tid - 256, 18, 26, tm11b, tm12b, tm21b, tm22b);
        unsigned short* bu = (unsigned short*)(smem + L_BAST);
        for (int n = tid - 256; n < 1744; n += 256) bu[n * 20 + 15] = 0;  // kill NaN*0
    }
    __syncthreads();   // B4: coeff + basisT ready; weights dead -> tm region

    // ---- phase 3: tm[16][1744] = coeff[16][15] . basisT[n][15]^T (MFMA) ----
    {
        const int nt = (wid < 5) ? 14 : 13;
        const int t0 = wid * 13 + ((wid < 5) ? wid : 5);
        unsigned short* tmu = (unsigned short*)(smem + L_TM);
#if HAVE_MFMA16
        const s4v ca = *(const s4v*)(smem + L_COEF + lrow * 10 + lkg * 2);
#endif
        for (int tt = 0; tt < nt; ++tt) {
            const int n0 = (t0 + tt) * 16;
            f4v d = {0.f, 0.f, 0.f, 0.f};
#if HAVE_MFMA16
            const s4v bb = *(const s4v*)(smem + L_BAST + (n0 + lrow) * 10 + lkg * 2);
            d = MFMA16(ca, bb, d);
#else
            const unsigned short* cf = (const unsigned short*)(smem + L_COEF);
            const unsigned short* bt = (const unsigned short*)(smem + L_BAST);
#pragma unroll
            for (int q = 0; q < 4; ++q) {
                float s = 0.f;
                for (int k = 0; k < 15; ++k)
                    s += frombf(cf[(lkg * 4 + q) * 20 + k]) * frombf(bt[(n0 + lrow) * 20 + k]);
                d[q] = s;
            }
#endif
#pragma unroll
            for (int q = 0; q < 4; ++q)
                tmu[(lkg * 4 + q) * 1744 + n0 + lrow] = tobf(d[q]);
        }
    }
    __syncthreads();   // B5: tm visible

    // ---- phase 4: banded mat-vec combos; wave handles rows 2w, 2w+1 ----
    {
        const int i   = lane;
        const int jlo = (i - 3 > 0) ? (i - 3) : 0;
        const int ne  = ((i + 3 < 63) ? (i + 3) : 63) - jlo + 1;
        const int base = (i < 4)  ? (i * (i + 7)) / 2
                       : (i <= 61) ? (7 * i - 6)
                       : (i == 62) ? 427 : 432;
        const float* pmf = (const float*)(smem + L_PMF);
        const float* cuf = (const float*)(smem + L_CUF);
        const float* clf = (const float*)(smem + L_CLF);
        const float* csf = (const float*)(smem + L_CSF);
        const uint2* tmr = (const uint2*)smem;   // tm at word 0: uint2 idx r*436+e

#pragma unroll
        for (int rr = 0; rr < 2; ++rr) {
            const int r  = wid * 2 + rr;
            const int gr = blockIdx.x * 16 + r;
            float nmu = 0.f, nml = 0.f, ncu = 0.f, ncl = 0.f, ncs = 0.f;
#pragma unroll
            for (int dd = 0; dd < 7; ++dd) {
                if (dd < ne) {
                    const int j = jlo + dd;
                    const uint2 tv = tmr[r * 436 + base + dd];
                    float t11 = lo16(tv.x);
                    float t12 = hi16(tv.x);
                    float t21 = lo16(tv.y);
                    float t22 = hi16(tv.y);
                    if (j == i) { t11 += 1.f; t22 += 1.f; }
                    const float mu  = pmf[r * 128 + j];
                    const float ml  = pmf[r * 128 + 64 + j];
                    const float vcu = cuf[r * 64 + j];
                    const float vcl = clf[r * 64 + j];
                    const float vcs = csf[r * 64 + j];
                    nmu += t11 * mu + t12 * ml;
                    nml += t21 * mu + t22 * ml;
                    ncu += t11 * t11 * vcu + 2.f * t11 * t12 * vcs + t12 * t12 * vcl;
                    ncl += t21 * t21 * vcu + 2.f * t21 * t22 * vcs + t22 * t22 * vcl;
                    ncs += t21 * t11 * vcu + (t22 * t11 + t21 * t12) * vcs + t22 * t12 * vcl;
                }
            }
            out[O_NM  + gr * 128 + i]      = nmu;
            out[O_NM  + gr * 128 + 64 + i] = nml;
            out[O_NCU + gr * 64 + i] = ncu + tcu;
            out[O_NCL + gr * 64 + i] = ncl + tcl;
            out[O_NCS + gr * 64 + i] = ncs;
        }
    }
}

extern "C" void kernel_launch(void* const* d_in, const int* in_sizes, int n_in,
                              void* d_out, int out_size, void* d_ws, size_t ws_size,
                              hipStream_t stream) {
    rkn_kernel<<<dim3(256), dim3(512), 0, stream>>>(
        (const float*)d_in[0],  // prior_mean
        (const float*)d_in[1],  // cov_u
        (const float*)d_in[2],  // cov_l
        (const float*)d_in[3],  // cov_s
        (const float*)d_in[4],  // obs
        (const float*)d_in[5],  // obs_var
        (const float*)d_in[6],  // W1
        (const float*)d_in[7],  // b1
        (const float*)d_in[8],  // W2
        (const float*)d_in[9],  // b2
        (const float*)d_in[10], // W3
        (const float*)d_in[11], // b3
        (const float*)d_in[12], // tm11_basis
        (const float*)d_in[13], // tm12_basis
        (const float*)d_in[14], // tm21_basis
        (const float*)d_in[15], // tm22_basis
        (const float*)d_in[16], // log_trans_noise
        (float*)d_out);
}

// Round 11
// 19.503 us; speedup vs baseline: 1.7770x; 1.3202x over previous
//
#include <hip/hip_runtime.h>
#include <math.h>

// RKN cell: B=4096, LOD=64, LSD=128, H=64, NB=15, NE=436 (band +-3)
// R11: R10 MFMA skeleton + conflict-free division-free basisT staging,
//      all staging hoisted before B1 (single overlapped prologue).
#define O_PM   0
#define O_PCU  524288
#define O_PCL  786432
#define O_PCS  1048576
#define O_NM   1310720
#define O_NCU  1835008
#define O_NCL  2097152
#define O_NCS  2359296

// ---- LDS word map (35808 words = 143232 B, 1 block/CU) ----
// W1L [64 j][76 w]; W2L [64 j][44 w]; W3L [16 j][44 w]
// tm  [16 r][872 w] = [16][1744] bf16  -- UNION with weights (dead after B4)
// BAST bas2[8 kp][1744 n] u32 = bf16 pair (k=2kp, 2kp+1); kp=7 hi-half = 0
// PMB bf16 [16][76 w]; H1/H2 bf16 [16 rows][44 w]; COEF [16 r][10 w]
// PMF f32 [16][128]; CUF/CLF/CSF f32 [16][64]
#define L_W1   0
#define L_W2   4864
#define L_W3   7680
#define L_TM   0
#define L_BAST 13952
#define L_PMB  27904
#define L_H1   29120
#define L_H2   29824
#define L_COEF 30528
#define L_PMF  30688
#define L_CUF  32736
#define L_CLF  33760
#define L_CSF  34784
#define L_TOT  35808

typedef short s8v __attribute__((ext_vector_type(8)));
typedef short s4v __attribute__((ext_vector_type(4)));
typedef float f4v __attribute__((ext_vector_type(4)));

__device__ __forceinline__ unsigned pk2(float a, float b) {   // 2xf32 -> 2xbf16 RNE
    unsigned ua = __float_as_uint(a), ub = __float_as_uint(b);
    ua += 0x7fffu + ((ua >> 16) & 1u);
    ub += 0x7fffu + ((ub >> 16) & 1u);
    return (ua >> 16) | (ub & 0xffff0000u);
}
__device__ __forceinline__ unsigned short tobf(float a) {
    unsigned ua = __float_as_uint(a);
    ua += 0x7fffu + ((ua >> 16) & 1u);
    return (unsigned short)(ua >> 16);
}
__device__ __forceinline__ float frombf(unsigned short u) {
    return __uint_as_float(((unsigned)u) << 16);
}
__device__ __forceinline__ float lo16(unsigned w) { return __uint_as_float(w << 16); }
__device__ __forceinline__ float hi16(unsigned w) { return __uint_as_float(w & 0xffff0000u); }
__device__ __forceinline__ float frcp(float x) { return __builtin_amdgcn_rcpf(x); }
__device__ __forceinline__ float ftanh(float x) {
    float e = __expf(2.f * x);
    return 1.f - 2.f * frcp(e + 1.f);
}
#define SWZ(v, imm) __uint_as_float((unsigned)__builtin_amdgcn_ds_swizzle((int)__float_as_uint(v), imm))

#if __has_builtin(__builtin_amdgcn_mfma_f32_16x16x16_bf16)
#define MFMA16(A,B,C) __builtin_amdgcn_mfma_f32_16x16x16_bf16(A,B,C,0,0,0)
#define HAVE_MFMA16 1
#elif __has_builtin(__builtin_amdgcn_mfma_f32_16x16x16bf16_1k)
#define MFMA16(A,B,C) __builtin_amdgcn_mfma_f32_16x16x16bf16_1k(A,B,C,0,0,0)
#define HAVE_MFMA16 1
#else
#define HAVE_MFMA16 0
#endif

__global__ __launch_bounds__(512, 2)
void rkn_kernel(const float* __restrict__ prior_mean,
                const float* __restrict__ cov_u,
                const float* __restrict__ cov_l,
                const float* __restrict__ cov_s,
                const float* __restrict__ obs,
                const float* __restrict__ obs_var,
                const float* __restrict__ W1,
                const float* __restrict__ b1,
                const float* __restrict__ W2,
                const float* __restrict__ b2,
                const float* __restrict__ W3,
                const float* __restrict__ b3,
                const float* __restrict__ tm11b,
                const float* __restrict__ tm12b,
                const float* __restrict__ tm21b,
                const float* __restrict__ tm22b,
                const float* __restrict__ ltn,
                float* __restrict__ out)
{
    __shared__ __align__(16) unsigned smem[L_TOT];

    const int tid  = threadIdx.x;
    const int wid  = tid >> 6;
    const int lane = tid & 63;
    const int lrow = lane & 15;     // MFMA operand row (A row / B col)
    const int lkg  = lane >> 4;     // k-group

    // ---- stage weights: coalesced float4 reads, bf16-pair LDS writes ----
    {
#pragma unroll
        for (int it = 0; it < 4; ++it) {              // W1: 2048 float4
            const int idx = it * 512 + tid;
            const float4 v = ((const float4*)W1)[idx];
            const int j = idx >> 5, kq = idx & 31;
            unsigned* d = smem + (L_W1 + j * 76 + kq * 2);
            d[0] = pk2(v.x, v.y); d[1] = pk2(v.z, v.w);
        }
#pragma unroll
        for (int it = 0; it < 2; ++it) {              // W2: 1024 float4
            const int idx = it * 512 + tid;
            const float4 v = ((const float4*)W2)[idx];
            const int j = idx >> 4, kq = idx & 15;
            unsigned* d = smem + (L_W2 + j * 44 + kq * 2);
            d[0] = pk2(v.x, v.y); d[1] = pk2(v.z, v.w);
        }
        if (tid < 240) {                              // W3: 15 j x 16 float4
            const float4 v = ((const float4*)W3)[tid];
            const int j = tid >> 4, kq = tid & 15;
            unsigned* d = smem + (L_W3 + j * 44 + kq * 2);
            d[0] = pk2(v.x, v.y); d[1] = pk2(v.z, v.w);
        } else if (tid < 284) {                       // zero W3 row 15
            smem[L_W3 + 15 * 44 + (tid - 240)] = 0u;
        }
    }

    // ---- stage basisT: bas2[kp][n] = pk2(b_m[2kp][e], b_m[2kp+1][e]), n=4e+m ----
    // Division-free (m = tid&3 fixed per lane), coalesced global reads,
    // lane-consecutive LDS writes (conflict-free). kp=7 hi half = 0 (k=15 pad).
    {
        const int m = tid & 3;
        const float* bp = (m == 0) ? tm11b : (m == 1) ? tm12b : (m == 2) ? tm21b : tm22b;
#pragma unroll
        for (int kp = 0; kp < 8; ++kp) {
#pragma unroll
            for (int c = 0; c < 4; ++c) {
                const int n = c * 512 + tid;
                if (n < 1744) {
                    const int e = n >> 2;
                    const float lo = bp[(2 * kp) * 436 + e];
                    const float hi = (kp < 7) ? bp[(2 * kp + 1) * 436 + e] : 0.f;
                    smem[L_BAST + kp * 1744 + n] = pk2(lo, hi);
                }
            }
        }
    }

    // ---- phase 1: Kalman (row = tid>>5, dims pd,pd+1) ----
    const int prow  = tid >> 5;
    const int pd    = (tid & 31) << 1;
    const int grow1 = blockIdx.x * 16 + prow;
    {
        const float2 cu2 = *(const float2*)(cov_u   + grow1 * 64 + pd);
        const float2 cl2 = *(const float2*)(cov_l   + grow1 * 64 + pd);
        const float2 cs2 = *(const float2*)(cov_s   + grow1 * 64 + pd);
        const float2 ob2 = *(const float2*)(obs     + grow1 * 64 + pd);
        const float2 ov2 = *(const float2*)(obs_var + grow1 * 64 + pd);
        const float2 pu2 = *(const float2*)(prior_mean + grow1 * 128 + pd);
        const float2 pl2 = *(const float2*)(prior_mean + grow1 * 128 + 64 + pd);

        const float i0 = frcp(cu2.x + ov2.x), i1 = frcp(cu2.y + ov2.y);
        const float qu0 = cu2.x * i0, qu1 = cu2.y * i1;
        const float ql0 = cs2.x * i0, ql1 = cs2.y * i1;
        const float r0 = ob2.x - pu2.x, r1 = ob2.y - pu2.y;
        const float pmu0 = pu2.x + qu0 * r0, pmu1 = pu2.y + qu1 * r1;
        const float pml0 = pl2.x + ql0 * r0, pml1 = pl2.y + ql1 * r1;
        const float cf0 = 1.f - qu0, cf1 = 1.f - qu1;
        const float pcu0 = cf0 * cu2.x, pcu1 = cf1 * cu2.y;
        const float pcl0 = cl2.x - ql0 * cs2.x, pcl1 = cl2.y - ql1 * cs2.y;
        const float pcs0 = cf0 * cs2.x, pcs1 = cf1 * cs2.y;

        *(float2*)(out + O_PM  + grow1 * 128 + pd)      = make_float2(pmu0, pmu1);
        *(float2*)(out + O_PM  + grow1 * 128 + 64 + pd) = make_float2(pml0, pml1);
        *(float2*)(out + O_PCU + grow1 * 64 + pd) = make_float2(pcu0, pcu1);
        *(float2*)(out + O_PCL + grow1 * 64 + pd) = make_float2(pcl0, pcl1);
        *(float2*)(out + O_PCS + grow1 * 64 + pd) = make_float2(pcs0, pcs1);

        smem[L_PMB + prow * 76 + (pd >> 1)]      = pk2(pmu0, pmu1);
        smem[L_PMB + prow * 76 + 32 + (pd >> 1)] = pk2(pml0, pml1);
        *(float2*)((float*)(smem + L_PMF) + prow * 128 + pd)      = make_float2(pmu0, pmu1);
        *(float2*)((float*)(smem + L_PMF) + prow * 128 + 64 + pd) = make_float2(pml0, pml1);
        *(float2*)((float*)(smem + L_CUF) + prow * 64 + pd) = make_float2(pcu0, pcu1);
        *(float2*)((float*)(smem + L_CLF) + prow * 64 + pd) = make_float2(pcl0, pcl1);
        *(float2*)((float*)(smem + L_CSF) + prow * 64 + pd) = make_float2(pcs0, pcs1);
    }

    // softplus(trans noise) for phase 4 (per lane)
    const float tcu = __logf(__expf(ltn[lane]) + 1.f);
    const float tcl = __logf(__expf(ltn[64 + lane]) + 1.f);

    __syncthreads();   // B1: weights + basisT + pm staged

    // ---- MLP ladder on waves 0-3 (waves 4-7 wait at barriers) ----
    if (wid < 4) {
        const int w = wid;
        f4v acc = {0.f, 0.f, 0.f, 0.f};
#pragma unroll
        for (int s = 0; s < 4; ++s) {                 // layer1: K=128
            s8v a = *(const s8v*)(smem + L_PMB + lrow * 76 + s * 16 + lkg * 4);
            s8v b = *(const s8v*)(smem + L_W1 + (w * 16 + lrow) * 76 + s * 16 + lkg * 4);
            acc = __builtin_amdgcn_mfma_f32_16x16x32_bf16(a, b, acc, 0, 0, 0);
        }
        const float bc1 = b1[w * 16 + lrow];
        unsigned short* h1u = (unsigned short*)(smem + L_H1);
#pragma unroll
        for (int q = 0; q < 4; ++q)
            h1u[(lkg * 4 + q) * 88 + w * 16 + lrow] = tobf(ftanh(acc[q] + bc1));
    }
    __syncthreads();   // B2: h1 ready

    if (wid < 4) {
        const int w = wid;
        f4v acc = {0.f, 0.f, 0.f, 0.f};
#pragma unroll
        for (int s = 0; s < 2; ++s) {                 // layer2: K=64
            s8v a = *(const s8v*)(smem + L_H1 + lrow * 44 + s * 16 + lkg * 4);
            s8v b = *(const s8v*)(smem + L_W2 + (w * 16 + lrow) * 44 + s * 16 + lkg * 4);
            acc = __builtin_amdgcn_mfma_f32_16x16x32_bf16(a, b, acc, 0, 0, 0);
        }
        const float bc2 = b2[w * 16 + lrow];
        unsigned short* h2u = (unsigned short*)(smem + L_H2);
#pragma unroll
        for (int q = 0; q < 4; ++q)
            h2u[(lkg * 4 + q) * 88 + w * 16 + lrow] = tobf(ftanh(acc[q] + bc2));
    }
    __syncthreads();   // B3: h2 ready

    if (wid < 4) {
        f4v acc = {0.f, 0.f, 0.f, 0.f};
#pragma unroll
        for (int s = 0; s < 2; ++s) {                 // layer3: K=64, cols 0-14
            s8v a = *(const s8v*)(smem + L_H2 + lrow * 44 + s * 16 + lkg * 4);
            s8v b = *(const s8v*)(smem + L_W3 + lrow * 44 + s * 16 + lkg * 4);
            acc = __builtin_amdgcn_mfma_f32_16x16x32_bf16(a, b, acc, 0, 0, 0);
        }
        const float bc3 = (lrow < 15) ? b3[lrow] : 0.f;
        unsigned short* cfu = (unsigned short*)(smem + L_COEF);
#pragma unroll
        for (int q = 0; q < 4; ++q) {                 // in-frag softmax over cols
            const float lg = acc[q] + bc3;
            float v = (lrow < 15) ? lg : -1e30f;
            v = fmaxf(v, SWZ(v, 0x041F));
            v = fmaxf(v, SWZ(v, 0x081F));
            v = fmaxf(v, SWZ(v, 0x101F));
            v = fmaxf(v, SWZ(v, 0x201F));
            const float ex = (lrow < 15) ? __expf(lg - v) : 0.f;
            float ss = ex;
            ss += SWZ(ss, 0x041F);
            ss += SWZ(ss, 0x081F);
            ss += SWZ(ss, 0x101F);
            ss += SWZ(ss, 0x201F);
            if (wid == 0)
                cfu[(lkg * 4 + q) * 20 + lrow] = tobf(ex * frcp(ss));
        }
    }
    __syncthreads();   // B4: coeff ready; weights dead -> tm region

    // ---- phase 3: tm[16][1744] = coeff[16][15] . basisT (MFMA, 8 waves) ----
    {
        const int nt = (wid < 5) ? 14 : 13;
        const int t0 = (wid < 5) ? wid * 14 : wid * 13 + 5;
        unsigned short* tmu = (unsigned short*)(smem + L_TM);
#if HAVE_MFMA16
        const s4v ca = *(const s4v*)(smem + L_COEF + lrow * 10 + lkg * 2);
#endif
        for (int tt = 0; tt < nt; ++tt) {
            const int n0 = (t0 + tt) * 16;
            const int nn = n0 + lrow;
            f4v d = {0.f, 0.f, 0.f, 0.f};
#if HAVE_MFMA16
            unsigned wpair[2];
            wpair[0] = smem[L_BAST + (lkg * 2    ) * 1744 + nn];
            wpair[1] = smem[L_BAST + (lkg * 2 + 1) * 1744 + nn];
            const s4v bb = *(const s4v*)wpair;
            d = MFMA16(ca, bb, d);
#else
            const unsigned short* cf = (const unsigned short*)(smem + L_COEF);
#pragma unroll
            for (int q = 0; q < 4; ++q) {
                float s = 0.f;
                for (int kp = 0; kp < 8; ++kp) {
                    const unsigned w = smem[L_BAST + kp * 1744 + nn];
                    s += lo16(w) * frombf(cf[(lkg * 4 + q) * 20 + 2 * kp]);
                    s += hi16(w) * frombf(cf[(lkg * 4 + q) * 20 + 2 * kp + 1]);
                }
                d[q] = s;
            }
#endif
#pragma unroll
            for (int q = 0; q < 4; ++q)
                tmu[(lkg * 4 + q) * 1744 + nn] = tobf(d[q]);
        }
    }
    __syncthreads();   // B5: tm visible

    // ---- phase 4: banded mat-vec combos; wave handles rows 2w, 2w+1 ----
    {
        const int i   = lane;
        const int jlo = (i - 3 > 0) ? (i - 3) : 0;
        const int ne  = ((i + 3 < 63) ? (i + 3) : 63) - jlo + 1;
        const int base = (i < 4)  ? (i * (i + 7)) / 2
                       : (i <= 61) ? (7 * i - 6)
                       : (i == 62) ? 427 : 432;
        const float* pmf = (const float*)(smem + L_PMF);
        const float* cuf = (const float*)(smem + L_CUF);
        const float* clf = (const float*)(smem + L_CLF);
        const float* csf = (const float*)(smem + L_CSF);
        const uint2* tmr = (const uint2*)smem;   // tm: uint2 idx r*436+e

#pragma unroll
        for (int rr = 0; rr < 2; ++rr) {
            const int r  = wid * 2 + rr;
            const int gr = blockIdx.x * 16 + r;
            float nmu = 0.f, nml = 0.f, ncu = 0.f, ncl = 0.f, ncs = 0.f;
#pragma unroll
            for (int dd = 0; dd < 7; ++dd) {
                if (dd < ne) {
                    const int j = jlo + dd;
                    const uint2 tv = tmr[r * 436 + base + dd];
                    float t11 = lo16(tv.x);
                    float t12 = hi16(tv.x);
                    float t21 = lo16(tv.y);
                    float t22 = hi16(tv.y);
                    if (j == i) { t11 += 1.f; t22 += 1.f; }
                    const float mu  = pmf[r * 128 + j];
                    const float ml  = pmf[r * 128 + 64 + j];
                    const float vcu = cuf[r * 64 + j];
                    const float vcl = clf[r * 64 + j];
                    const float vcs = csf[r * 64 + j];
                    nmu += t11 * mu + t12 * ml;
                    nml += t21 * mu + t22 * ml;
                    ncu += t11 * t11 * vcu + 2.f * t11 * t12 * vcs + t12 * t12 * vcl;
                    ncl += t21 * t21 * vcu + 2.f * t21 * t22 * vcs + t22 * t22 * vcl;
                    ncs += t21 * t11 * vcu + (t22 * t11 + t21 * t12) * vcs + t22 * t12 * vcl;
                }
            }
            out[O_NM  + gr * 128 + i]      = nmu;
            out[O_NM  + gr * 128 + 64 + i] = nml;
            out[O_NCU + gr * 64 + i] = ncu + tcu;
            out[O_NCL + gr * 64 + i] = ncl + tcl;
            out[O_NCS + gr * 64 + i] = ncs;
        }
    }
}

extern "C" void kernel_launch(void* const* d_in, const int* in_sizes, int n_in,
                              void* d_out, int out_size, void* d_ws, size_t ws_size,
                              hipStream_t stream) {
    rkn_kernel<<<dim3(256), dim3(512), 0, stream>>>(
        (const float*)d_in[0],  // prior_mean
        (const float*)d_in[1],  // cov_u
        (const float*)d_in[2],  // cov_l
        (const float*)d_in[3],  // cov_s
        (const float*)d_in[4],  // obs
        (const float*)d_in[5],  // obs_var
        (const float*)d_in[6],  // W1
        (const float*)d_in[7],  // b1
        (const float*)d_in[8],  // W2
        (const float*)d_in[9],  // b2
        (const float*)d_in[10], // W3
        (const float*)d_in[11], // b3
        (const float*)d_in[12], // tm11_basis
        (const float*)d_in[13], // tm12_basis
        (const float*)d_in[14], // tm21_basis
        (const float*)d_in[15], // tm22_basis
        (const float*)d_in[16], // log_trans_noise
        (float*)d_out);
}